// Round 4
// baseline (876.586 us; speedup 1.0000x reference)
//
#include <hip/hip_runtime.h>
#include <hip/hip_bf16.h>

#define N_IN 128
#define N_OUT 64
#define BSHIFT 7                 // 128 nodes per bucket
#define BNODES 128
#define MAXB 1024                // supports nN up to 131072

// ---- count: degS (out-degree, global atomics) + bucket histogram (LDS-reduced) ----
__global__ __launch_bounds__(256) void count_kernel(const int* __restrict__ src,
                                                    const int* __restrict__ dst,
                                                    int* __restrict__ degS,
                                                    int* __restrict__ cntB,
                                                    int nE, int nB) {
    __shared__ int h[MAXB];
    int t = threadIdx.x;
    for (int i = t; i < nB; i += 256) h[i] = 0;
    __syncthreads();
    int i = blockIdx.x * 256 + t;
    int stride = gridDim.x * 256;
    for (; i < nE; i += stride) {
        atomicAdd(&degS[src[i]], 1);
        atomicAdd(&h[dst[i] >> BSHIFT], 1);
    }
    __syncthreads();
    for (int j = t; j < nB; j += 256) {
        int c = h[j];
        if (c) atomicAdd(&cntB[j], c);
    }
}

// ---- norm = rsqrt(max(degS,1)) written over degS ----
__global__ void norm_kernel(int* __restrict__ degS, float* __restrict__ nrm, int nN) {
    int i = blockIdx.x * blockDim.x + threadIdx.x;
    if (i < nN) {
        float d = (float)degS[i];
        nrm[i] = rsqrtf(fmaxf(d, 1.0f));
    }
}

// ---- single-block exclusive scan of cntB -> base, cursor (nB <= 1024) ----
__global__ __launch_bounds__(256) void scanB_kernel(const int* __restrict__ cntB,
                                                    int* __restrict__ base,
                                                    int* __restrict__ cursor, int nB) {
    __shared__ int sh[256];
    int t = threadIdx.x;
    int v[4];
    int s = 0;
#pragma unroll
    for (int i = 0; i < 4; ++i) {
        int idx = t * 4 + i;
        v[i] = (idx < nB) ? cntB[idx] : 0;
        s += v[i];
    }
    sh[t] = s;
    __syncthreads();
    for (int o = 1; o < 256; o <<= 1) {
        int x = (t >= o) ? sh[t - o] : 0;
        __syncthreads();
        sh[t] += x;
        __syncthreads();
    }
    int run = (t == 0) ? 0 : sh[t - 1];
#pragma unroll
    for (int i = 0; i < 4; ++i) {
        int idx = t * 4 + i;
        if (idx < nB) { base[idx] = run; cursor[idx] = run; }
        run += v[i];
    }
}

// ---- bucketed fill: register-stage 8192 edges, LDS hist, reserve, scatter packed u32 ----
__global__ __launch_bounds__(512) void fillB_kernel(const int* __restrict__ src,
                                                    const int* __restrict__ dst,
                                                    int* __restrict__ cursor,
                                                    unsigned int* __restrict__ buf,
                                                    int nE, int nB) {
    __shared__ int hist[MAXB];
    __shared__ int lbase[MAXB];
    int t = threadIdx.x;
    for (int i = t; i < nB; i += 512) hist[i] = 0;
    __syncthreads();

    int e0 = blockIdx.x * 8192 + t;
    unsigned int pk[16];
    int bk[16];
#pragma unroll
    for (int j = 0; j < 16; ++j) {
        int e = e0 + j * 512;
        if (e < nE) {
            int s = src[e], d = dst[e];
            bk[j] = d >> BSHIFT;
            pk[j] = ((unsigned int)s << BSHIFT) | (unsigned int)(d & (BNODES - 1));
            atomicAdd(&hist[bk[j]], 1);
        } else {
            bk[j] = -1;
        }
    }
    __syncthreads();
    for (int i = t; i < nB; i += 512) {
        int c = hist[i];
        lbase[i] = c ? atomicAdd(&cursor[i], c) : 0;
    }
    __syncthreads();
#pragma unroll
    for (int j = 0; j < 16; ++j) {
        if (bk[j] >= 0) {
            int pos = atomicAdd(&lbase[bk[j]], 1);
            buf[pos] = pk[j];
        }
    }
}

// ---- h = bf16( (feat @ W) * norm[:,None] ) ----
__global__ __launch_bounds__(512) void gemm_kernel(const float* __restrict__ feat,
                                                   const float* __restrict__ w,
                                                   const float* __restrict__ nrm,
                                                   __hip_bfloat16* __restrict__ h, int nN) {
    __shared__ float wl[N_IN][N_OUT];   // 32 KB
    __shared__ float fl[8][N_IN];       // 4 KB
    int t = threadIdx.x;
    for (int i = t; i < N_IN * N_OUT; i += 512) ((float*)wl)[i] = w[i];
    int nodeBase = blockIdx.x * 8;
    for (int i = t; i < 8 * N_IN; i += 512) {
        int node = nodeBase + i / N_IN;
        ((float*)fl)[i] = (node < nN) ? feat[(size_t)node * N_IN + (i & (N_IN - 1))] : 0.0f;
    }
    __syncthreads();

    int g = t >> 6, col = t & 63;
    int node = nodeBase + g;
    if (node >= nN) return;

    float acc = 0.0f;
#pragma unroll
    for (int k = 0; k < N_IN; ++k) acc += fl[g][k] * wl[k][col];
    h[(size_t)node * N_OUT + col] = __float2bfloat16(acc * nrm[node]);
}

// ---- aggregate: one block per bucket, LDS fp32 accumulator, fused norm+bias epilogue ----
__global__ __launch_bounds__(512) void agg_kernel(const unsigned int* __restrict__ buf,
                                                  const int* __restrict__ base,
                                                  const int* __restrict__ cursor,
                                                  const __hip_bfloat16* __restrict__ h,
                                                  const float* __restrict__ nrm,
                                                  const float* __restrict__ bias,
                                                  float* __restrict__ out, int nN) {
    __shared__ float acc[BNODES * N_OUT];   // 32 KB
    int t = threadIdx.x;
    int lane = t & 63, wv = t >> 6;          // 8 waves
    for (int i = t; i < BNODES * N_OUT; i += 512) acc[i] = 0.0f;
    __syncthreads();

    int b = blockIdx.x;
    int start = base[b];
    int end = cursor[b];                     // after fill, cursor == end

    int e = start + wv;
    for (; e + 8 < end; e += 16) {           // 2 strided edges in flight per wave
        unsigned int p0 = buf[e];
        unsigned int p1 = buf[e + 8];
        int s0 = p0 >> BSHIFT, o0 = p0 & (BNODES - 1);
        int s1 = p1 >> BSHIFT, o1 = p1 & (BNODES - 1);
        float v0 = __bfloat162float(h[(size_t)s0 * N_OUT + lane]);
        float v1 = __bfloat162float(h[(size_t)s1 * N_OUT + lane]);
        unsafeAtomicAdd(&acc[o0 * N_OUT + lane], v0);
        unsafeAtomicAdd(&acc[o1 * N_OUT + lane], v1);
    }
    if (e < end) {
        unsigned int p = buf[e];
        int s = p >> BSHIFT, o = p & (BNODES - 1);
        float v = __bfloat162float(h[(size_t)s * N_OUT + lane]);
        unsafeAtomicAdd(&acc[o * N_OUT + lane], v);
    }
    __syncthreads();

    float bl = bias[lane];
    int nodeBase = b * BNODES;
    for (int r = wv; r < BNODES; r += 8) {
        int node = nodeBase + r;
        if (node < nN)
            out[(size_t)node * N_OUT + lane] = acc[r * N_OUT + lane] * nrm[node] + bl;
    }
}

extern "C" void kernel_launch(void* const* d_in, const int* in_sizes, int n_in,
                              void* d_out, int out_size, void* d_ws, size_t ws_size,
                              hipStream_t stream) {
    const float* feat = (const float*)d_in[0];
    const float* w    = (const float*)d_in[1];
    const float* bias = (const float*)d_in[2];
    const int*   src  = (const int*)d_in[3];
    const int*   dst  = (const int*)d_in[4];
    float* out = (float*)d_out;

    int nN = in_sizes[0] / N_IN;      // 100000
    int nE = in_sizes[3];             // 1600000
    int nB = (nN + BNODES - 1) >> BSHIFT;   // 782

    // ---- workspace layout (~19.7 MB; round-3 proved ws >= ~20.8 MB) ----
    size_t o = 0;
    auto alloc = [&](size_t bytes) { size_t r = o; o = (o + bytes + 1023) & ~(size_t)1023; return r; };
    char* wsc = (char*)d_ws;
    int* degS   = (int*)(wsc + alloc((size_t)nN * 4));   // becomes nrm (float) in place
    int* cntB   = (int*)(wsc + alloc((size_t)MAXB * 4));
    int* base   = (int*)(wsc + alloc((size_t)MAXB * 4));
    int* cursor = (int*)(wsc + alloc((size_t)MAXB * 4));
    unsigned int* buf = (unsigned int*)(wsc + alloc((size_t)nE * 4));
    __hip_bfloat16* h = (__hip_bfloat16*)(wsc + alloc((size_t)nN * N_OUT * 2));
    float* nrm = (float*)degS;

    hipMemsetAsync(degS, 0, (size_t)nN * 4, stream);
    hipMemsetAsync(cntB, 0, (size_t)MAXB * 4, stream);

    count_kernel<<<256, 256, 0, stream>>>(src, dst, degS, cntB, nE, nB);
    norm_kernel<<<(nN + 255) / 256, 256, 0, stream>>>(degS, nrm, nN);
    scanB_kernel<<<1, 256, 0, stream>>>(cntB, base, cursor, nB);
    fillB_kernel<<<(nE + 8191) / 8192, 512, 0, stream>>>(src, dst, cursor, buf, nE, nB);
    gemm_kernel<<<(nN + 7) / 8, 512, 0, stream>>>(feat, w, nrm, h, nN);
    agg_kernel<<<nB, 512, 0, stream>>>(buf, base, cursor, h, nrm, bias, out, nN);
}

// Round 5
// 232.559 us; speedup vs baseline: 3.7693x; 3.7693x over previous
//
#include <hip/hip_runtime.h>
#include <hip/hip_bf16.h>

#define N_IN 128
#define N_OUT 64
#define BSHIFT 7                 // 128 nodes per bucket
#define BNODES 128
#define MAXB 1024                // supports nN up to 131072
#define CH 4096                  // edges per agg chunk

// ---- count: degS (out-degree, global atomics) + bucket histogram (LDS-reduced) ----
__global__ __launch_bounds__(256) void count_kernel(const int* __restrict__ src,
                                                    const int* __restrict__ dst,
                                                    int* __restrict__ degS,
                                                    int* __restrict__ cntB,
                                                    int nE, int nB) {
    __shared__ int h[MAXB];
    int t = threadIdx.x;
    for (int i = t; i < nB; i += 256) h[i] = 0;
    __syncthreads();
    int i = blockIdx.x * 256 + t;
    int stride = gridDim.x * 256;
    for (; i < nE; i += stride) {
        atomicAdd(&degS[src[i]], 1);
        atomicAdd(&h[dst[i] >> BSHIFT], 1);
    }
    __syncthreads();
    for (int j = t; j < nB; j += 256) {
        int c = h[j];
        if (c) atomicAdd(&cntB[j], c);
    }
}

// ---- norm = rsqrt(max(degS,1)) written over degS ----
__global__ void norm_kernel(int* __restrict__ degS, float* __restrict__ nrm, int nN) {
    int i = blockIdx.x * blockDim.x + threadIdx.x;
    if (i < nN) {
        float d = (float)degS[i];
        nrm[i] = rsqrtf(fmaxf(d, 1.0f));
    }
}

// ---- single-block exclusive scan of cntB -> base, cursor (nB <= 1024) ----
__global__ __launch_bounds__(256) void scanB_kernel(const int* __restrict__ cntB,
                                                    int* __restrict__ base,
                                                    int* __restrict__ cursor, int nB) {
    __shared__ int sh[256];
    int t = threadIdx.x;
    int v[4];
    int s = 0;
#pragma unroll
    for (int i = 0; i < 4; ++i) {
        int idx = t * 4 + i;
        v[i] = (idx < nB) ? cntB[idx] : 0;
        s += v[i];
    }
    sh[t] = s;
    __syncthreads();
    for (int o = 1; o < 256; o <<= 1) {
        int x = (t >= o) ? sh[t - o] : 0;
        __syncthreads();
        sh[t] += x;
        __syncthreads();
    }
    int run = (t == 0) ? 0 : sh[t - 1];
#pragma unroll
    for (int i = 0; i < 4; ++i) {
        int idx = t * 4 + i;
        if (idx < nB) { base[idx] = run; cursor[idx] = run; }
        run += v[i];
    }
}

// ---- bucketed fill: register-stage 8192 edges, LDS hist, reserve, scatter packed u32 ----
__global__ __launch_bounds__(512) void fillB_kernel(const int* __restrict__ src,
                                                    const int* __restrict__ dst,
                                                    int* __restrict__ cursor,
                                                    unsigned int* __restrict__ buf,
                                                    int nE, int nB) {
    __shared__ int hist[MAXB];
    __shared__ int lbase[MAXB];
    int t = threadIdx.x;
    for (int i = t; i < nB; i += 512) hist[i] = 0;
    __syncthreads();

    int e0 = blockIdx.x * 8192 + t;
    unsigned int pk[16];
    int bk[16];
#pragma unroll
    for (int j = 0; j < 16; ++j) {
        int e = e0 + j * 512;
        if (e < nE) {
            int s = src[e], d = dst[e];
            bk[j] = d >> BSHIFT;
            pk[j] = ((unsigned int)s << BSHIFT) | (unsigned int)(d & (BNODES - 1));
            atomicAdd(&hist[bk[j]], 1);
        } else {
            bk[j] = -1;
        }
    }
    __syncthreads();
    for (int i = t; i < nB; i += 512) {
        int c = hist[i];
        lbase[i] = c ? atomicAdd(&cursor[i], c) : 0;
    }
    __syncthreads();
#pragma unroll
    for (int j = 0; j < 16; ++j) {
        if (bk[j] >= 0) {
            int pos = atomicAdd(&lbase[bk[j]], 1);
            buf[pos] = pk[j];
        }
    }
}

// ---- h = bf16( (feat @ W) * norm[:,None] ), 4-node x 4-col register tile ----
// block 256 threads = 16 colgroups x 16 gq; covers 64 nodes (4 per thread, stride 16)
__global__ __launch_bounds__(256) void gemm_kernel(const float* __restrict__ feat,
                                                   const float* __restrict__ w,
                                                   const float* __restrict__ nrm,
                                                   __hip_bfloat16* __restrict__ h, int nN) {
    __shared__ float wl[N_IN][N_OUT];       // 32 KB
    __shared__ float fl[64][N_IN + 4];      // pad 4 floats: rows start in banks {0,4,8,12}
    int t = threadIdx.x;
    for (int i = t; i < N_IN * N_OUT; i += 256) ((float*)wl)[i] = w[i];
    int nodeBase = blockIdx.x * 64;
    for (int i = t; i < 64 * N_IN; i += 256) {
        int r = i >> 7, k = i & (N_IN - 1);
        int node = nodeBase + r;
        fl[r][k] = (node < nN) ? feat[(size_t)node * N_IN + k] : 0.0f;
    }
    __syncthreads();

    int c4 = t & 15;        // col group (cols c4*4 .. +3)
    int gq = t >> 4;        // 0..15; nodes gq + 16*j
    float acc[4][4];
#pragma unroll
    for (int j = 0; j < 4; ++j)
#pragma unroll
        for (int c = 0; c < 4; ++c) acc[j][c] = 0.0f;

    for (int k4 = 0; k4 < N_IN / 4; ++k4) {
        float4 w0 = *(const float4*)&wl[k4 * 4 + 0][c4 * 4];
        float4 w1 = *(const float4*)&wl[k4 * 4 + 1][c4 * 4];
        float4 w2 = *(const float4*)&wl[k4 * 4 + 2][c4 * 4];
        float4 w3 = *(const float4*)&wl[k4 * 4 + 3][c4 * 4];
#pragma unroll
        for (int j = 0; j < 4; ++j) {
            float4 f = *(const float4*)&fl[gq + 16 * j][k4 * 4];
            acc[j][0] += f.x * w0.x + f.y * w1.x + f.z * w2.x + f.w * w3.x;
            acc[j][1] += f.x * w0.y + f.y * w1.y + f.z * w2.y + f.w * w3.y;
            acc[j][2] += f.x * w0.z + f.y * w1.z + f.z * w2.z + f.w * w3.z;
            acc[j][3] += f.x * w0.w + f.y * w1.w + f.z * w2.w + f.w * w3.w;
        }
    }

#pragma unroll
    for (int j = 0; j < 4; ++j) {
        int node = nodeBase + gq + 16 * j;
        if (node < nN) {
            float nn = nrm[node];
            union { ushort4 u4; __hip_bfloat16 b[4]; } pkk;
            pkk.b[0] = __float2bfloat16(acc[j][0] * nn);
            pkk.b[1] = __float2bfloat16(acc[j][1] * nn);
            pkk.b[2] = __float2bfloat16(acc[j][2] * nn);
            pkk.b[3] = __float2bfloat16(acc[j][3] * nn);
            *(ushort4*)&h[(size_t)node * N_OUT + c4 * 4] = pkk.u4;
        }
    }
}

// ---- aggregate: per bucket, LDS counting-sort then register accumulation. NO atomic fp. ----
__global__ __launch_bounds__(512) void agg_kernel(const unsigned int* __restrict__ buf,
                                                  const int* __restrict__ base,
                                                  const int* __restrict__ cursor,
                                                  const __hip_bfloat16* __restrict__ h,
                                                  const float* __restrict__ nrm,
                                                  const float* __restrict__ bias,
                                                  float* __restrict__ out, int nN) {
    __shared__ unsigned int sorted[CH];     // 16 KB
    __shared__ int hist[BNODES];
    __shared__ int ssh[BNODES];
    __shared__ int sbase[BNODES];
    __shared__ int scur[BNODES];
    int t = threadIdx.x;
    int lane = t & 63, wv = t >> 6;          // 8 waves, wave owns rows wv*16..+15

    int b = blockIdx.x;
    int start = base[b];
    int end = cursor[b];

    float acc[16];
#pragma unroll
    for (int r = 0; r < 16; ++r) acc[r] = 0.0f;

    for (int c0 = start; c0 < end; c0 += CH) {
        int cnt = min(end - c0, CH);
        for (int i = t; i < BNODES; i += 512) hist[i] = 0;
        __syncthreads();

        unsigned int pk[CH / 512];
#pragma unroll
        for (int j = 0; j < CH / 512; ++j) {
            int e = t + j * 512;
            if (e < cnt) {
                pk[j] = buf[c0 + e];
                atomicAdd(&hist[pk[j] & (BNODES - 1)], 1);
            } else {
                pk[j] = 0xFFFFFFFFu;         // never a valid packed value (s < 2^24 scale)
            }
        }
        __syncthreads();

        // exclusive scan of hist[128]
        if (t < BNODES) ssh[t] = hist[t];
        __syncthreads();
        for (int o = 1; o < BNODES; o <<= 1) {
            int x = 0;
            if (t < BNODES && t >= o) x = ssh[t - o];
            __syncthreads();
            if (t < BNODES) ssh[t] += x;
            __syncthreads();
        }
        if (t < BNODES) {
            int ex = (t == 0) ? 0 : ssh[t - 1];
            sbase[t] = ex;
            scur[t] = ex;
        }
        __syncthreads();

        // scatter into sorted
#pragma unroll
        for (int j = 0; j < CH / 512; ++j) {
            if (pk[j] != 0xFFFFFFFFu) {
                int pos = atomicAdd(&scur[pk[j] & (BNODES - 1)], 1);
                sorted[pos] = pk[j];
            }
        }
        __syncthreads();                     // scur[r] now == row end

        // wave-owned row accumulation (sorted[] reads are wave-broadcast)
#pragma unroll
        for (int r = 0; r < 16; ++r) {
            int row = wv * 16 + r;
            int e = sbase[row], eend = scur[row];
            float a = acc[r];
            for (; e + 1 < eend; e += 2) {
                int s0 = (int)(sorted[e] >> BSHIFT);
                int s1 = (int)(sorted[e + 1] >> BSHIFT);
                float v0 = __bfloat162float(h[(size_t)s0 * N_OUT + lane]);
                float v1 = __bfloat162float(h[(size_t)s1 * N_OUT + lane]);
                a += v0;
                a += v1;
            }
            if (e < eend) a += __bfloat162float(h[(size_t)(sorted[e] >> BSHIFT) * N_OUT + lane]);
            acc[r] = a;
        }
        __syncthreads();                     // protect sorted/hist before next chunk
    }

    // epilogue straight from registers
    float bl = bias[lane];
    int nodeBase = b * BNODES + wv * 16;
#pragma unroll
    for (int r = 0; r < 16; ++r) {
        int node = nodeBase + r;
        if (node < nN)
            out[(size_t)node * N_OUT + lane] = acc[r] * nrm[node] + bl;
    }
}

extern "C" void kernel_launch(void* const* d_in, const int* in_sizes, int n_in,
                              void* d_out, int out_size, void* d_ws, size_t ws_size,
                              hipStream_t stream) {
    const float* feat = (const float*)d_in[0];
    const float* w    = (const float*)d_in[1];
    const float* bias = (const float*)d_in[2];
    const int*   src  = (const int*)d_in[3];
    const int*   dst  = (const int*)d_in[4];
    float* out = (float*)d_out;

    int nN = in_sizes[0] / N_IN;      // 100000
    int nE = in_sizes[3];             // 1600000
    int nB = (nN + BNODES - 1) >> BSHIFT;   // 782

    // ---- workspace layout (~19.7 MB) ----
    size_t o = 0;
    auto alloc = [&](size_t bytes) { size_t r = o; o = (o + bytes + 1023) & ~(size_t)1023; return r; };
    char* wsc = (char*)d_ws;
    int* degS   = (int*)(wsc + alloc((size_t)nN * 4));   // becomes nrm (float) in place
    int* cntB   = (int*)(wsc + alloc((size_t)MAXB * 4));
    int* base   = (int*)(wsc + alloc((size_t)MAXB * 4));
    int* cursor = (int*)(wsc + alloc((size_t)MAXB * 4));
    unsigned int* buf = (unsigned int*)(wsc + alloc((size_t)nE * 4));
    __hip_bfloat16* h = (__hip_bfloat16*)(wsc + alloc((size_t)nN * N_OUT * 2));
    float* nrm = (float*)degS;

    hipMemsetAsync(degS, 0, (size_t)nN * 4, stream);
    hipMemsetAsync(cntB, 0, (size_t)MAXB * 4, stream);

    count_kernel<<<256, 256, 0, stream>>>(src, dst, degS, cntB, nE, nB);
    norm_kernel<<<(nN + 255) / 256, 256, 0, stream>>>(degS, nrm, nN);
    scanB_kernel<<<1, 256, 0, stream>>>(cntB, base, cursor, nB);
    fillB_kernel<<<(nE + 8191) / 8192, 512, 0, stream>>>(src, dst, cursor, buf, nE, nB);
    gemm_kernel<<<(nN + 63) / 64, 256, 0, stream>>>(feat, w, nrm, h, nN);
    agg_kernel<<<nB, 512, 0, stream>>>(buf, base, cursor, h, nrm, bias, out, nN);
}

// Round 6
// 187.049 us; speedup vs baseline: 4.6864x; 1.2433x over previous
//
#include <hip/hip_runtime.h>
#include <hip/hip_bf16.h>

#define N_IN 128
#define N_OUT 64
#define BSHIFT 7                 // 128 nodes per bucket
#define BNODES 128
#define MAXB 1024                // supports nN up to 131072
#define CH 4096                  // edges per agg chunk

typedef short bf16x8 __attribute__((ext_vector_type(8)));
typedef float f32x4 __attribute__((ext_vector_type(4)));

__device__ inline short f2bf(float x) {
    __hip_bfloat16 b = __float2bfloat16(x);
    union { __hip_bfloat16 b; short s; } u;
    u.b = b;
    return u.s;
}

// ---- count: degS (out-degree, global atomics) + bucket histogram (LDS-reduced) ----
__global__ __launch_bounds__(256) void count_kernel(const int* __restrict__ src,
                                                    const int* __restrict__ dst,
                                                    int* __restrict__ degS,
                                                    int* __restrict__ cntB,
                                                    int nE, int nB) {
    __shared__ int h[MAXB];
    int t = threadIdx.x;
    for (int i = t; i < nB; i += 256) h[i] = 0;
    __syncthreads();
    int i = blockIdx.x * 256 + t;
    int stride = gridDim.x * 256;
    for (; i < nE; i += stride) {
        atomicAdd(&degS[src[i]], 1);
        atomicAdd(&h[dst[i] >> BSHIFT], 1);
    }
    __syncthreads();
    for (int j = t; j < nB; j += 256) {
        int c = h[j];
        if (c) atomicAdd(&cntB[j], c);
    }
}

// ---- norm = rsqrt(max(degS,1)) written over degS ----
__global__ void norm_kernel(int* __restrict__ degS, float* __restrict__ nrm, int nN) {
    int i = blockIdx.x * blockDim.x + threadIdx.x;
    if (i < nN) {
        float d = (float)degS[i];
        nrm[i] = rsqrtf(fmaxf(d, 1.0f));
    }
}

// ---- single-block exclusive scan of cntB -> base, cursor (nB <= 1024) ----
__global__ __launch_bounds__(256) void scanB_kernel(const int* __restrict__ cntB,
                                                    int* __restrict__ base,
                                                    int* __restrict__ cursor, int nB) {
    __shared__ int sh[256];
    int t = threadIdx.x;
    int v[4];
    int s = 0;
#pragma unroll
    for (int i = 0; i < 4; ++i) {
        int idx = t * 4 + i;
        v[i] = (idx < nB) ? cntB[idx] : 0;
        s += v[i];
    }
    sh[t] = s;
    __syncthreads();
    for (int o = 1; o < 256; o <<= 1) {
        int x = (t >= o) ? sh[t - o] : 0;
        __syncthreads();
        sh[t] += x;
        __syncthreads();
    }
    int run = (t == 0) ? 0 : sh[t - 1];
#pragma unroll
    for (int i = 0; i < 4; ++i) {
        int idx = t * 4 + i;
        if (idx < nB) { base[idx] = run; cursor[idx] = run; }
        run += v[i];
    }
}

// ---- bucketed fill: register-stage 8192 edges, LDS hist, reserve, scatter packed u32 ----
__global__ __launch_bounds__(512) void fillB_kernel(const int* __restrict__ src,
                                                    const int* __restrict__ dst,
                                                    int* __restrict__ cursor,
                                                    unsigned int* __restrict__ buf,
                                                    int nE, int nB) {
    __shared__ int hist[MAXB];
    __shared__ int lbase[MAXB];
    int t = threadIdx.x;
    for (int i = t; i < nB; i += 512) hist[i] = 0;
    __syncthreads();

    int e0 = blockIdx.x * 8192 + t;
    unsigned int pk[16];
    int bk[16];
#pragma unroll
    for (int j = 0; j < 16; ++j) {
        int e = e0 + j * 512;
        if (e < nE) {
            int s = src[e], d = dst[e];
            bk[j] = d >> BSHIFT;
            pk[j] = ((unsigned int)s << BSHIFT) | (unsigned int)(d & (BNODES - 1));
            atomicAdd(&hist[bk[j]], 1);
        } else {
            bk[j] = -1;
        }
    }
    __syncthreads();
    for (int i = t; i < nB; i += 512) {
        int c = hist[i];
        lbase[i] = c ? atomicAdd(&cursor[i], c) : 0;
    }
    __syncthreads();
#pragma unroll
    for (int j = 0; j < 16; ++j) {
        if (bk[j] >= 0) {
            int pos = atomicAdd(&lbase[bk[j]], 1);
            buf[pos] = pk[j];
        }
    }
}

// ---- h = bf16( (feat @ W) * norm[:,None] ) via MFMA 16x16x32 bf16 ----
// block = 256 threads = 4 waves; wave w computes rows [blk*64 + 16w, +16), all 64 cols.
__global__ __launch_bounds__(256) void gemm_kernel(const float* __restrict__ feat,
                                                   const float* __restrict__ w,
                                                   const float* __restrict__ nrm,
                                                   __hip_bfloat16* __restrict__ h, int nN) {
    __shared__ short wt[N_OUT][N_IN + 8];    // W^T as bf16 bits, pad 8 shorts (17.4 KB)
    int t = threadIdx.x;
    for (int i = t; i < N_IN * N_OUT; i += 256) {
        int k = i >> 6, c = i & 63;
        wt[c][k] = f2bf(w[i]);
    }
    __syncthreads();

    int wv = t >> 6, l = t & 63;
    int c16 = l & 15;          // A row idx within tile / B col idx / D col idx
    int kq  = l >> 4;          // k-quad 0..3 (8 k's each)
    int nodeBase = blockIdx.x * 64 + wv * 16;
    int rowA = nodeBase + c16;
    int rowAc = min(rowA, nN - 1);                 // clamp loads; stores masked

    f32x4 acc[4];
#pragma unroll
    for (int ct = 0; ct < 4; ++ct) acc[ct] = (f32x4){0.f, 0.f, 0.f, 0.f};

    const float* fptr = feat + (size_t)rowAc * N_IN + kq * 8;
#pragma unroll
    for (int ks = 0; ks < 4; ++ks) {
        float4 a0 = *(const float4*)(fptr + ks * 32);
        float4 a1 = *(const float4*)(fptr + ks * 32 + 4);
        union { bf16x8 v; short s[8]; } af;
        af.s[0] = f2bf(a0.x); af.s[1] = f2bf(a0.y);
        af.s[2] = f2bf(a0.z); af.s[3] = f2bf(a0.w);
        af.s[4] = f2bf(a1.x); af.s[5] = f2bf(a1.y);
        af.s[6] = f2bf(a1.z); af.s[7] = f2bf(a1.w);
#pragma unroll
        for (int ct = 0; ct < 4; ++ct) {
            bf16x8 bf = *(const bf16x8*)&wt[ct * 16 + c16][ks * 32 + kq * 8];
            acc[ct] = __builtin_amdgcn_mfma_f32_16x16x32_bf16(af.v, bf, acc[ct], 0, 0, 0);
        }
    }

    // D layout (m89-verified): col = lane&15, row = 4*(lane>>4) + reg
#pragma unroll
    for (int r = 0; r < 4; ++r) {
        int node = nodeBase + 4 * kq + r;
        if (node < nN) {
            float nn = nrm[node];
#pragma unroll
            for (int ct = 0; ct < 4; ++ct) {
                short v = f2bf(acc[ct][r] * nn);
                *(short*)&h[(size_t)node * N_OUT + ct * 16 + c16] = v;
            }
        }
    }
}

// ---- aggregate: per bucket, LDS counting-sort then register accumulation. NO atomic fp. ----
__global__ __launch_bounds__(512) void agg_kernel(const unsigned int* __restrict__ buf,
                                                  const int* __restrict__ base,
                                                  const int* __restrict__ cursor,
                                                  const __hip_bfloat16* __restrict__ h,
                                                  const float* __restrict__ nrm,
                                                  const float* __restrict__ bias,
                                                  float* __restrict__ out, int nN) {
    __shared__ unsigned int sorted[CH];     // 16 KB
    __shared__ int hist[BNODES];
    __shared__ int ssh[BNODES];
    __shared__ int sbase[BNODES];
    __shared__ int scur[BNODES];
    int t = threadIdx.x;
    int lane = t & 63, wv = t >> 6;          // 8 waves, wave owns rows wv*16..+15

    int b = blockIdx.x;
    int start = base[b];
    int end = cursor[b];

    float acc[16];
#pragma unroll
    for (int r = 0; r < 16; ++r) acc[r] = 0.0f;

    for (int c0 = start; c0 < end; c0 += CH) {
        int cnt = min(end - c0, CH);
        for (int i = t; i < BNODES; i += 512) hist[i] = 0;
        __syncthreads();

        unsigned int pk[CH / 512];
#pragma unroll
        for (int j = 0; j < CH / 512; ++j) {
            int e = t + j * 512;
            if (e < cnt) {
                pk[j] = buf[c0 + e];
                atomicAdd(&hist[pk[j] & (BNODES - 1)], 1);
            } else {
                pk[j] = 0xFFFFFFFFu;
            }
        }
        __syncthreads();

        // exclusive scan of hist[128]
        if (t < BNODES) ssh[t] = hist[t];
        __syncthreads();
        for (int o = 1; o < BNODES; o <<= 1) {
            int x = 0;
            if (t < BNODES && t >= o) x = ssh[t - o];
            __syncthreads();
            if (t < BNODES) ssh[t] += x;
            __syncthreads();
        }
        if (t < BNODES) {
            int ex = (t == 0) ? 0 : ssh[t - 1];
            sbase[t] = ex;
            scur[t] = ex;
        }
        __syncthreads();

        // scatter into sorted
#pragma unroll
        for (int j = 0; j < CH / 512; ++j) {
            if (pk[j] != 0xFFFFFFFFu) {
                int pos = atomicAdd(&scur[pk[j] & (BNODES - 1)], 1);
                sorted[pos] = pk[j];
            }
        }
        __syncthreads();                     // scur[r] now == row end

        // wave-owned row accumulation (sorted[] reads are wave-broadcast)
#pragma unroll
        for (int r = 0; r < 16; ++r) {
            int row = wv * 16 + r;
            int e = sbase[row], eend = scur[row];
            float a = acc[r];
            for (; e + 1 < eend; e += 2) {
                int s0 = (int)(sorted[e] >> BSHIFT);
                int s1 = (int)(sorted[e + 1] >> BSHIFT);
                float v0 = __bfloat162float(h[(size_t)s0 * N_OUT + lane]);
                float v1 = __bfloat162float(h[(size_t)s1 * N_OUT + lane]);
                a += v0;
                a += v1;
            }
            if (e < eend) a += __bfloat162float(h[(size_t)(sorted[e] >> BSHIFT) * N_OUT + lane]);
            acc[r] = a;
        }
        __syncthreads();                     // protect sorted/hist before next chunk
    }

    // epilogue straight from registers
    float bl = bias[lane];
    int nodeBase = b * BNODES + wv * 16;
#pragma unroll
    for (int r = 0; r < 16; ++r) {
        int node = nodeBase + r;
        if (node < nN)
            out[(size_t)node * N_OUT + lane] = acc[r] * nrm[node] + bl;
    }
}

extern "C" void kernel_launch(void* const* d_in, const int* in_sizes, int n_in,
                              void* d_out, int out_size, void* d_ws, size_t ws_size,
                              hipStream_t stream) {
    const float* feat = (const float*)d_in[0];
    const float* w    = (const float*)d_in[1];
    const float* bias = (const float*)d_in[2];
    const int*   src  = (const int*)d_in[3];
    const int*   dst  = (const int*)d_in[4];
    float* out = (float*)d_out;

    int nN = in_sizes[0] / N_IN;      // 100000
    int nE = in_sizes[3];             // 1600000
    int nB = (nN + BNODES - 1) >> BSHIFT;   // 782

    // ---- workspace layout (~19.7 MB) ----
    size_t o = 0;
    auto alloc = [&](size_t bytes) { size_t r = o; o = (o + bytes + 1023) & ~(size_t)1023; return r; };
    char* wsc = (char*)d_ws;
    int* degS   = (int*)(wsc + alloc((size_t)nN * 4));   // becomes nrm (float) in place
    int* cntB   = (int*)(wsc + alloc((size_t)MAXB * 4));
    int* base   = (int*)(wsc + alloc((size_t)MAXB * 4));
    int* cursor = (int*)(wsc + alloc((size_t)MAXB * 4));
    unsigned int* buf = (unsigned int*)(wsc + alloc((size_t)nE * 4));
    __hip_bfloat16* h = (__hip_bfloat16*)(wsc + alloc((size_t)nN * N_OUT * 2));
    float* nrm = (float*)degS;

    hipMemsetAsync(degS, 0, (size_t)nN * 4, stream);
    hipMemsetAsync(cntB, 0, (size_t)MAXB * 4, stream);

    count_kernel<<<256, 256, 0, stream>>>(src, dst, degS, cntB, nE, nB);
    norm_kernel<<<(nN + 255) / 256, 256, 0, stream>>>(degS, nrm, nN);
    scanB_kernel<<<1, 256, 0, stream>>>(cntB, base, cursor, nB);
    fillB_kernel<<<(nE + 8191) / 8192, 512, 0, stream>>>(src, dst, cursor, buf, nE, nB);
    gemm_kernel<<<(nN + 63) / 64, 256, 0, stream>>>(feat, w, nrm, h, nN);
    agg_kernel<<<nB, 512, 0, stream>>>(buf, base, cursor, h, nrm, bias, out, nN);
}